// Round 13
// baseline (452.758 us; speedup 1.0000x reference)
//
#include <hip/hip_runtime.h>

#define HIDDEN 256
#define NGRAPH 1024
#define EPS 1e-6f
#define STAGE_ROWS 156    // slab head staged in LDS (~156 KB of the 160 KiB/CU)
#define CACHE_ROWS 704    // last ~704 rows per slab cacheable (~180 MB aggregate < 256 MB L3)

typedef float f32x4 __attribute__((ext_vector_type(4)));

__device__ __forceinline__ float ssum(const f32x4 v) {
    return v.x * v.x + v.y * v.y + v.z * v.z + v.w * v.w;
}

// One block per graph (batch sorted => graph g owns contiguous rows [start,end)).
//
// r13 change (single semantic diff vs r12): phase-B TAIL reads use REGULAR
// cacheable loads, not NT. Theory under test: MUBUF `nt` loads bypass the L3
// probe, so r6-r12's phase-B re-reads NEVER hit the lines phase A cached —
// pinning us at ~2.9 GB of HBM traffic (6.7 TB/s at 432 us = the ceiling).
// Regular loads should consume the ~180 MB tail window phase A allocated.
//
// Cache policy per region:
//   rows 0..155   : phase A NT load -> LDS stage; phase B from LDS.
//   middle        : NT load both phases (conceded HBM re-read, out of L3).
//   last 704 rows : phase A cacheable (allocates L3), phase B cacheable (hits).
// All output via NT stores (write stream must not evict x).
//
// 156 KB static LDS forces 1 block/CU (256 resident blocks).
__global__ __launch_bounds__(1024) void k_fused(
    const float* __restrict__ x, const int* __restrict__ batch,
    const float* __restrict__ w, float* __restrict__ out, int n_nodes) {

    __shared__ float smem[STAGE_ROWS * HIDDEN + 16];   // stage + reduce scratch

    const int g    = (int)blockIdx.x;
    const int tid  = (int)threadIdx.x;
    const int lane = tid & 63;
    const int wid  = tid >> 6;      // 0..15

    // Binary-search graph bounds (wave-uniform broadcast loads, ~40 total).
    int lo = 0, hi = n_nodes;
    while (lo < hi) { int m = (lo + hi) >> 1; if (batch[m] < g) lo = m + 1; else hi = m; }
    const int start = lo;
    int lo2 = start, hi2 = n_nodes;
    while (lo2 < hi2) { int m = (lo2 + hi2) >> 1; if (batch[m] < g + 1) lo2 = m + 1; else hi2 = m; }
    const int count = lo2 - start;
    if (count <= 0) return;         // block-uniform: safe w.r.t. __syncthreads below

    const int nsweep = (count + 127) >> 7;                       // 16 waves x 8 rows
    const int cache_from_row = (count > CACHE_ROWS) ? (count - CACHE_ROWS) : 0;

    // ---- Phase A: sum of squares, explicit per-region cache policy ----
    float acc = 0.0f;
    for (int s = 0; s < nsweep; ++s) {
        const int base = (s << 7) + (wid << 3);
        if (base + 8 <= count) {
            f32x4 v[8];
            if (base + 8 <= STAGE_ROWS) {
                // Head: NT load + LDS stage.
                #pragma unroll
                for (int k = 0; k < 8; ++k)
                    v[k] = __builtin_nontemporal_load(reinterpret_cast<const f32x4*>(
                        x + (size_t)(start + base + k) * HIDDEN + (size_t)lane * 4));
                #pragma unroll
                for (int k = 0; k < 8; ++k)
                    *reinterpret_cast<f32x4*>(&smem[(base + k) * HIDDEN + lane * 4]) = v[k];
            } else if (base >= cache_from_row) {
                // Tail window: cacheable (the only L3-allocating stream).
                #pragma unroll
                for (int k = 0; k < 8; ++k)
                    v[k] = *reinterpret_cast<const f32x4*>(
                        x + (size_t)(start + base + k) * HIDDEN + (size_t)lane * 4);
            } else {
                // Middle: NT load, no L3 allocation.
                #pragma unroll
                for (int k = 0; k < 8; ++k)
                    v[k] = __builtin_nontemporal_load(reinterpret_cast<const f32x4*>(
                        x + (size_t)(start + base + k) * HIDDEN + (size_t)lane * 4));
            }
            #pragma unroll
            for (int k = 0; k < 8; ++k) acc += ssum(v[k]);
        } else {
            for (int r = base; r < count; ++r)
                acc += ssum(*reinterpret_cast<const f32x4*>(
                    x + (size_t)(start + r) * HIDDEN + (size_t)lane * 4));
        }
    }
    #pragma unroll
    for (int off = 32; off > 0; off >>= 1)
        acc += __shfl_xor(acc, off);
    if (lane == 0) smem[STAGE_ROWS * HIDDEN + wid] = acc;
    __syncthreads();

    float total = 0.0f;
    #pragma unroll
    for (int k = 0; k < 16; ++k) total += smem[STAGE_ROWS * HIDDEN + k];
    const float mean = total / ((float)count * (float)HIDDEN);
    const float rr   = 1.0f / sqrtf(mean + EPS);

    // ---- Phase B: reverse sweep order; LDS head, cacheable tail, NT middle ----
    const f32x4 wv = *reinterpret_cast<const f32x4*>(w + (size_t)lane * 4);
    for (int s = nsweep - 1; s >= 0; --s) {
        const int base = (s << 7) + (wid << 3);
        if (base + 8 <= count) {
            f32x4 v[8];
            if (base + 8 <= STAGE_ROWS) {   // staged in phase A by THIS wave
                #pragma unroll
                for (int k = 0; k < 8; ++k)
                    v[k] = *reinterpret_cast<const f32x4*>(
                        &smem[(base + k) * HIDDEN + lane * 4]);
            } else if (base >= cache_from_row) {
                // Tail: REGULAR load — must be able to consume the L3 lines
                // phase A allocated (NT loads appear to bypass the probe).
                #pragma unroll
                for (int k = 0; k < 8; ++k)
                    v[k] = *reinterpret_cast<const f32x4*>(
                        x + (size_t)(start + base + k) * HIDDEN + (size_t)lane * 4);
            } else {
                // Middle: NT load (conceded HBM re-read, keep out of L3).
                #pragma unroll
                for (int k = 0; k < 8; ++k)
                    v[k] = __builtin_nontemporal_load(reinterpret_cast<const f32x4*>(
                        x + (size_t)(start + base + k) * HIDDEN + (size_t)lane * 4));
            }
            #pragma unroll
            for (int k = 0; k < 8; ++k) {
                f32x4 o = { v[k].x * wv.x * rr, v[k].y * wv.y * rr,
                            v[k].z * wv.z * rr, v[k].w * wv.w * rr };
                __builtin_nontemporal_store(o, reinterpret_cast<f32x4*>(
                    out + (size_t)(start + base + k) * HIDDEN + (size_t)lane * 4));
            }
        } else {
            for (int r = base; r < count; ++r) {
                const f32x4 v = *reinterpret_cast<const f32x4*>(
                    x + (size_t)(start + r) * HIDDEN + (size_t)lane * 4);
                f32x4 o = { v.x * wv.x * rr, v.y * wv.y * rr,
                            v.z * wv.z * rr, v.w * wv.w * rr };
                __builtin_nontemporal_store(o, reinterpret_cast<f32x4*>(
                    out + (size_t)(start + r) * HIDDEN + (size_t)lane * 4));
            }
        }
    }
}

extern "C" void kernel_launch(void* const* d_in, const int* in_sizes, int n_in,
                              void* d_out, int out_size, void* d_ws, size_t ws_size,
                              hipStream_t stream) {
    const float* x     = (const float*)d_in[0];
    const int*   batch = (const int*)d_in[1];
    const float* w     = (const float*)d_in[2];
    float*       out   = (float*)d_out;
    const int n_nodes  = in_sizes[1];

    // One block per graph; 1024 threads = 16 waves; 156 KB LDS -> 1 block/CU.
    k_fused<<<NGRAPH, 1024, 0, stream>>>(x, batch, w, out, n_nodes);
}

// Round 14
// 431.304 us; speedup vs baseline: 1.0497x; 1.0497x over previous
//
#include <hip/hip_runtime.h>

#define HIDDEN 256
#define NGRAPH 1024
#define EPS 1e-6f
#define STAGE_ROWS 156    // slab head staged in LDS (~156 KB of the 160 KiB/CU)
#define CACHE_ROWS 704    // last ~704 rows per slab cacheable in phase A

typedef float f32x4 __attribute__((ext_vector_type(4)));

__device__ __forceinline__ float ssum(const f32x4 v) {
    return v.x * v.x + v.y * v.y + v.z * v.z + v.w * v.w;
}

// One block per graph (batch sorted => graph g owns contiguous rows [start,end)).
// FINAL (r14 = revert to r12, best measured 432 us):
//
// Phase A: stream the slab; rows 0..155 NT-load + LDS stage; middle NT;
//          tail cacheable. Per-lane SS accumulate, block reduce.
// Phase B: reverse sweep order; head from LDS, rest NT loads; NT stores.
//
// Why this is the floor (evidence r10-r13): the 256 MB Infinity Cache is
// memory-side and flag-insensitive — it serves ~25% of the phase-B re-read
// (the ~256 MB of most-recent phase-A lines) regardless of nt/cacheable
// policy, occupancy, or window sizing. Effective HBM bytes ~= 1.02 (A) +
// ~0.6 (B misses) + 1.02 (write) ~= 2.6 GB at ~6.1 TB/s ~= 432 us, vs
// 6.3 TB/s documented achievable. LDS staging covers 15% of the re-read;
// register staging regressed (r8/r9: spill + scheduler serialization).
//
// 156 KB static LDS forces 1 block/CU (256 resident blocks, 4 rounds).
__global__ __launch_bounds__(1024) void k_fused(
    const float* __restrict__ x, const int* __restrict__ batch,
    const float* __restrict__ w, float* __restrict__ out, int n_nodes) {

    __shared__ float smem[STAGE_ROWS * HIDDEN + 16];   // stage + reduce scratch

    const int g    = (int)blockIdx.x;
    const int tid  = (int)threadIdx.x;
    const int lane = tid & 63;
    const int wid  = tid >> 6;      // 0..15

    // Binary-search graph bounds (wave-uniform broadcast loads, ~40 total).
    int lo = 0, hi = n_nodes;
    while (lo < hi) { int m = (lo + hi) >> 1; if (batch[m] < g) lo = m + 1; else hi = m; }
    const int start = lo;
    int lo2 = start, hi2 = n_nodes;
    while (lo2 < hi2) { int m = (lo2 + hi2) >> 1; if (batch[m] < g + 1) lo2 = m + 1; else hi2 = m; }
    const int count = lo2 - start;
    if (count <= 0) return;         // block-uniform: safe w.r.t. __syncthreads below

    const int nsweep = (count + 127) >> 7;                       // 16 waves x 8 rows
    const int cache_from_row = (count > CACHE_ROWS) ? (count - CACHE_ROWS) : 0;

    // ---- Phase A: sum of squares ----
    float acc = 0.0f;
    for (int s = 0; s < nsweep; ++s) {
        const int base = (s << 7) + (wid << 3);
        if (base + 8 <= count) {
            f32x4 v[8];
            if (base + 8 <= STAGE_ROWS) {
                // Head: NT load + LDS stage.
                #pragma unroll
                for (int k = 0; k < 8; ++k)
                    v[k] = __builtin_nontemporal_load(reinterpret_cast<const f32x4*>(
                        x + (size_t)(start + base + k) * HIDDEN + (size_t)lane * 4));
                #pragma unroll
                for (int k = 0; k < 8; ++k)
                    *reinterpret_cast<f32x4*>(&smem[(base + k) * HIDDEN + lane * 4]) = v[k];
            } else if (base >= cache_from_row) {
                // Tail window: cacheable.
                #pragma unroll
                for (int k = 0; k < 8; ++k)
                    v[k] = *reinterpret_cast<const f32x4*>(
                        x + (size_t)(start + base + k) * HIDDEN + (size_t)lane * 4);
            } else {
                // Middle: NT load.
                #pragma unroll
                for (int k = 0; k < 8; ++k)
                    v[k] = __builtin_nontemporal_load(reinterpret_cast<const f32x4*>(
                        x + (size_t)(start + base + k) * HIDDEN + (size_t)lane * 4));
            }
            #pragma unroll
            for (int k = 0; k < 8; ++k) acc += ssum(v[k]);
        } else {
            for (int r = base; r < count; ++r)
                acc += ssum(*reinterpret_cast<const f32x4*>(
                    x + (size_t)(start + r) * HIDDEN + (size_t)lane * 4));
        }
    }
    #pragma unroll
    for (int off = 32; off > 0; off >>= 1)
        acc += __shfl_xor(acc, off);
    if (lane == 0) smem[STAGE_ROWS * HIDDEN + wid] = acc;
    __syncthreads();

    float total = 0.0f;
    #pragma unroll
    for (int k = 0; k < 16; ++k) total += smem[STAGE_ROWS * HIDDEN + k];
    const float mean = total / ((float)count * (float)HIDDEN);
    const float rr   = 1.0f / sqrtf(mean + EPS);

    // ---- Phase B: normalize; reverse sweep order; LDS head + NT loads; NT stores ----
    const f32x4 wv = *reinterpret_cast<const f32x4*>(w + (size_t)lane * 4);
    for (int s = nsweep - 1; s >= 0; --s) {
        const int base = (s << 7) + (wid << 3);
        if (base + 8 <= count) {
            f32x4 v[8];
            if (base + 8 <= STAGE_ROWS) {   // staged in phase A by THIS wave
                #pragma unroll
                for (int k = 0; k < 8; ++k)
                    v[k] = *reinterpret_cast<const f32x4*>(
                        &smem[(base + k) * HIDDEN + lane * 4]);
            } else {
                #pragma unroll
                for (int k = 0; k < 8; ++k)
                    v[k] = __builtin_nontemporal_load(reinterpret_cast<const f32x4*>(
                        x + (size_t)(start + base + k) * HIDDEN + (size_t)lane * 4));
            }
            #pragma unroll
            for (int k = 0; k < 8; ++k) {
                f32x4 o = { v[k].x * wv.x * rr, v[k].y * wv.y * rr,
                            v[k].z * wv.z * rr, v[k].w * wv.w * rr };
                __builtin_nontemporal_store(o, reinterpret_cast<f32x4*>(
                    out + (size_t)(start + base + k) * HIDDEN + (size_t)lane * 4));
            }
        } else {
            for (int r = base; r < count; ++r) {
                const f32x4 v = __builtin_nontemporal_load(reinterpret_cast<const f32x4*>(
                    x + (size_t)(start + r) * HIDDEN + (size_t)lane * 4));
                f32x4 o = { v.x * wv.x * rr, v.y * wv.y * rr,
                            v.z * wv.z * rr, v.w * wv.w * rr };
                __builtin_nontemporal_store(o, reinterpret_cast<f32x4*>(
                    out + (size_t)(start + r) * HIDDEN + (size_t)lane * 4));
            }
        }
    }
}

extern "C" void kernel_launch(void* const* d_in, const int* in_sizes, int n_in,
                              void* d_out, int out_size, void* d_ws, size_t ws_size,
                              hipStream_t stream) {
    const float* x     = (const float*)d_in[0];
    const int*   batch = (const int*)d_in[1];
    const float* w     = (const float*)d_in[2];
    float*       out   = (float*)d_out;
    const int n_nodes  = in_sizes[1];

    // One block per graph; 1024 threads = 16 waves; 156 KB LDS -> 1 block/CU.
    k_fused<<<NGRAPH, 1024, 0, stream>>>(x, batch, w, out, n_nodes);
}